// Round 1
// baseline (542.102 us; speedup 1.0000x reference)
//
#include <hip/hip_runtime.h>
#include <hip/hip_bf16.h>

#define D 768
#define BM 64
#define LDX 776          // padded x-tile row length (bf16 elems): +8 kills bank conflicts
#define NWAVE 8
#define NTAB 512         // ND
#define NS 64

typedef short short8v __attribute__((ext_vector_type(8)));
typedef float f32x4 __attribute__((ext_vector_type(4)));

static __device__ __forceinline__ unsigned short f2bf(float f) {
    union { float f; unsigned u; } v; v.f = f;
    unsigned r = v.u + 0x7fffu + ((v.u >> 16) & 1u);   // RNE
    return (unsigned short)(r >> 16);
}

static __device__ __forceinline__ float fast_tanh(float x) {
    // tanh(x) = 1 - 2/(e^{2x}+1); saturates correctly for large |x|
    float e = __expf(2.0f * x);
    return 1.0f - 2.0f * __builtin_amdgcn_rcpf(e + 1.0f);
}

static __device__ __forceinline__ float dot4(float4 a, float4 b) {
    return a.x * b.x + a.y * b.y + a.z * b.z + a.w * b.w;
}

// ---------------- flag prep ----------------
__global__ void k_zero_flags(int* flags) {
    if (threadIdx.x < NTAB) flags[threadIdx.x] = 0;
}

__global__ void k_scan_pairs(const int* __restrict__ pairs, int* __restrict__ flags, int B) {
    int i = blockIdx.x * blockDim.x + threadIdx.x;
    if (i < B) {
        int idx = pairs[(size_t)i * 3];
        if (idx >= 0 && idx < NTAB) atomicOr(&flags[idx], 1);
    }
}

// ---------------- W fp32 -> bf16 ----------------
__global__ void k_convert_w(const float* __restrict__ wb_f, const float* __restrict__ wa_f,
                            unsigned short* __restrict__ wb, unsigned short* __restrict__ wa) {
    int i = blockIdx.x * blockDim.x + threadIdx.x;     // one float4 per thread
    if (i < D * D / 4) {
        float4 vb = ((const float4*)wb_f)[i];
        float4 va = ((const float4*)wa_f)[i];
        ushort4 ub = { f2bf(vb.x), f2bf(vb.y), f2bf(vb.z), f2bf(vb.w) };
        ushort4 ua = { f2bf(va.x), f2bf(va.y), f2bf(va.z), f2bf(va.w) };
        ((ushort4*)wb)[i] = ub;
        ((ushort4*)wa)[i] = ua;
    }
}

// ---------------- gather tables: T[d][s][2] for the three projections ----------------
__global__ void k_tables(const float* __restrict__ db, const float* __restrict__ da,
                         const float* __restrict__ W1b, const float* __restrict__ W2b,
                         const float* __restrict__ W1a, const float* __restrict__ W2a,
                         const int* __restrict__ flags,
                         float* __restrict__ T1b, float* __restrict__ T2b, float* __restrict__ Ta) {
    int d = blockIdx.x;
    if (!flags[d]) return;                              // only rows that pairs actually index
    int lane = threadIdx.x & 63;
    int wid = threadIdx.x >> 6;                         // 0..3

    float4 a0[3], a1[3], b0[3], b1[3], c0[3], c1[3];    // weights held in regs
    #pragma unroll
    for (int i = 0; i < 3; ++i) {
        a0[i] = ((const float4*)W1b)[lane + 64 * i];
        a1[i] = ((const float4*)(W1b + D))[lane + 64 * i];
        b0[i] = ((const float4*)W2b)[lane + 64 * i];
        b1[i] = ((const float4*)(W2b + D))[lane + 64 * i];
        float4 p = ((const float4*)W1a)[lane + 64 * i];
        float4 q = ((const float4*)W2a)[lane + 64 * i];
        c0[i] = make_float4(p.x + q.x, p.y + q.y, p.z + q.z, p.w + q.w);
        p = ((const float4*)(W1a + D))[lane + 64 * i];
        q = ((const float4*)(W2a + D))[lane + 64 * i];
        c1[i] = make_float4(p.x + q.x, p.y + q.y, p.z + q.z, p.w + q.w);
    }

    for (int s = wid; s < NS; s += 4) {
        size_t roff = ((size_t)d * NS + s) * D;
        const float4* rb = (const float4*)(db + roff);
        const float4* ra = (const float4*)(da + roff);
        float sa0 = 0, sa1 = 0, sb0 = 0, sb1 = 0, sc0 = 0, sc1 = 0;
        #pragma unroll
        for (int i = 0; i < 3; ++i) {
            float4 xb = rb[lane + 64 * i];
            float4 xa = ra[lane + 64 * i];
            sa0 += dot4(xb, a0[i]); sa1 += dot4(xb, a1[i]);
            sb0 += dot4(xb, b0[i]); sb1 += dot4(xb, b1[i]);
            sc0 += dot4(xa, c0[i]); sc1 += dot4(xa, c1[i]);
        }
        #pragma unroll
        for (int off = 32; off; off >>= 1) {
            sa0 += __shfl_xor(sa0, off); sa1 += __shfl_xor(sa1, off);
            sb0 += __shfl_xor(sb0, off); sb1 += __shfl_xor(sb1, off);
            sc0 += __shfl_xor(sc0, off); sc1 += __shfl_xor(sc1, off);
        }
        if (lane == 0) {
            size_t o = ((size_t)d * NS + s) * 2;
            T1b[o] = sa0; T1b[o + 1] = sa1;
            T2b[o] = sb0; T2b[o + 1] = sb1;
            Ta[o]  = sc0; Ta[o + 1]  = sc1;
        }
    }
}

// ---------------- fused main: bf16 MFMA GEMM + tanh + 768->2 projection + gather ----------------
__global__ __launch_bounds__(512, 1)
void k_main(const float* __restrict__ xbert, const float* __restrict__ xalb,
            const unsigned short* __restrict__ wb, const unsigned short* __restrict__ wa,
            const float* __restrict__ bdb, const float* __restrict__ bda,
            const float* __restrict__ wpb, const float* __restrict__ wpa,
            const int* __restrict__ pairs,
            const float* __restrict__ T1b, const float* __restrict__ T2b, const float* __restrict__ Ta,
            const float* __restrict__ bpb, const float* __restrict__ bpa,
            const float* __restrict__ b1b, const float* __restrict__ b2b,
            const float* __restrict__ b1a, const float* __restrict__ b2a,
            float* __restrict__ out) {
    __shared__ short xs[BM * LDX];                       // 99,328 B
    __shared__ float outp[NWAVE][BM][2];                 //  4,096 B

    const int tid = threadIdx.x;
    const int lane = tid & 63;
    const int wid = tid >> 6;                            // 0..7
    const int l15 = lane & 15;
    const int lhi = lane >> 4;                           // 0..3
    const int nb = wid * 96;                             // this wave's n-range (96 cols)
    float outv = 0.0f;

    for (int m = 0; m < 2; ++m) {
        const float* xg = m ? xalb : xbert;
        const unsigned short* wg = m ? wa : wb;
        const float* bd = m ? bda : bdb;
        const float* wp = m ? wpa : wpb;

        // ---- stage x tile fp32 -> bf16 LDS ----
        const float4* xg4 = (const float4*)xg + (size_t)blockIdx.x * (BM * D / 4);
        for (int i = tid; i < BM * D / 4; i += 512) {
            int row = i / (D / 4);
            int c4 = i % (D / 4);
            float4 v = xg4[i];
            ushort4 u = { f2bf(v.x), f2bf(v.y), f2bf(v.z), f2bf(v.w) };
            *(ushort4*)(&xs[row * LDX + c4 * 4]) = u;
        }
        __syncthreads();

        // ---- GEMM: acc[4 m-frags][6 n-frags], K=768 ----
        f32x4 acc[4][6];
        #pragma unroll
        for (int mi = 0; mi < 4; ++mi)
            #pragma unroll
            for (int ni = 0; ni < 6; ++ni)
                acc[mi][ni] = (f32x4){0.f, 0.f, 0.f, 0.f};

        #pragma unroll 2
        for (int kk = 0; kk < 24; ++kk) {
            const int kb = kk * 32 + lhi * 8;
            short8v av[4];
            #pragma unroll
            for (int mi = 0; mi < 4; ++mi)
                av[mi] = *(const short8v*)(&xs[(mi * 16 + l15) * LDX + kb]);
            short8v bv[6];
            #pragma unroll
            for (int ni = 0; ni < 6; ++ni)
                bv[ni] = *(const short8v*)((const short*)wg + (size_t)(nb + ni * 16 + l15) * D + kb);
            #pragma unroll
            for (int mi = 0; mi < 4; ++mi)
                #pragma unroll
                for (int ni = 0; ni < 6; ++ni)
                    acc[mi][ni] = __builtin_amdgcn_mfma_f32_16x16x32_bf16(av[mi], bv[ni], acc[mi][ni], 0, 0, 0);
        }

        // ---- epilogue: tanh + project to 2 cols, partial per lane ----
        float bdv[6], w0v[6], w1v[6];
        #pragma unroll
        for (int ni = 0; ni < 6; ++ni) {
            int n = nb + ni * 16 + l15;
            bdv[ni] = bd[n];
            w0v[ni] = wp[n];
            w1v[ni] = wp[D + n];
        }
        float ps[4][4][2] = {};
        #pragma unroll
        for (int mi = 0; mi < 4; ++mi)
            #pragma unroll
            for (int ni = 0; ni < 6; ++ni)
                #pragma unroll
                for (int r = 0; r < 4; ++r) {
                    float t = fast_tanh(acc[mi][ni][r] + bdv[ni]);
                    ps[mi][r][0] += t * w0v[ni];
                    ps[mi][r][1] += t * w1v[ni];
                }
        // reduce over the 16 lanes (l15) that share a row
        #pragma unroll
        for (int mi = 0; mi < 4; ++mi)
            #pragma unroll
            for (int r = 0; r < 4; ++r)
                #pragma unroll
                for (int c = 0; c < 2; ++c) {
                    float v = ps[mi][r][c];
                    v += __shfl_xor(v, 1);
                    v += __shfl_xor(v, 2);
                    v += __shfl_xor(v, 4);
                    v += __shfl_xor(v, 8);
                    ps[mi][r][c] = v;
                }
        if (l15 == 0) {
            #pragma unroll
            for (int mi = 0; mi < 4; ++mi)
                #pragma unroll
                for (int r = 0; r < 4; ++r) {
                    int row = mi * 16 + lhi * 4 + r;
                    outp[wid][row][0] = ps[mi][r][0];
                    outp[wid][row][1] = ps[mi][r][1];
                }
        }
        __syncthreads();
        if (tid < 128) {
            int row = tid >> 1, c = tid & 1;
            float s = 0.0f;
            #pragma unroll
            for (int w = 0; w < NWAVE; ++w) s += outp[w][row][c];
            outv += s;
        }
        // next model's staging may proceed; outp is rewritten only after the next barrier
    }

    // ---- gather + biases + final write (one write per output, no atomics) ----
    if (tid < 128) {
        int row = tid >> 1, c = tid & 1;
        size_t R = (size_t)blockIdx.x * BM + row;
        const int* pr = pairs + R * 3;
        int i0 = pr[0], j = pr[1], k2 = pr[2];
        float g = T1b[((size_t)i0 * NS + j) * 2 + c]
                + T2b[((size_t)i0 * NS + k2) * 2 + c]
                + Ta[((size_t)i0 * NS + j) * 2 + c];
        float bias = bpb[c] + bpa[c] + b1b[c] + b2b[c] + b1a[c] + b2a[c];
        out[R * 2 + c] = outv + g + bias;
    }
}

extern "C" void kernel_launch(void* const* d_in, const int* in_sizes, int n_in,
                              void* d_out, int out_size, void* d_ws, size_t ws_size,
                              hipStream_t stream) {
    const float* xb   = (const float*)d_in[0];
    const float* db   = (const float*)d_in[1];
    const int*   pairs= (const int*)d_in[2];
    const float* xa   = (const float*)d_in[3];
    const float* da   = (const float*)d_in[4];
    const float* Wdb  = (const float*)d_in[5];
    const float* bdb  = (const float*)d_in[6];
    const float* Wda  = (const float*)d_in[7];
    const float* bda  = (const float*)d_in[8];
    const float* Wpb  = (const float*)d_in[9];
    const float* bpb  = (const float*)d_in[10];
    const float* Wpa  = (const float*)d_in[11];
    const float* bpa  = (const float*)d_in[12];
    const float* W1b  = (const float*)d_in[13];
    const float* b1b  = (const float*)d_in[14];
    const float* W2b  = (const float*)d_in[15];
    const float* b2b  = (const float*)d_in[16];
    const float* W1a  = (const float*)d_in[17];
    const float* b1a  = (const float*)d_in[18];
    const float* W2a  = (const float*)d_in[19];
    const float* b2a  = (const float*)d_in[20];
    float* out = (float*)d_out;

    const int B = in_sizes[0] / D;                       // 65536

    char* ws = (char*)d_ws;
    int* flags = (int*)ws;
    unsigned short* Wb = (unsigned short*)(ws + 2048);
    unsigned short* Wa = Wb + D * D;
    float* T1b = (float*)(ws + 2048 + (size_t)2 * D * D * sizeof(unsigned short));
    float* T2b = T1b + NTAB * NS * 2;
    float* Ta  = T2b + NTAB * NS * 2;

    k_zero_flags<<<1, 512, 0, stream>>>(flags);
    k_scan_pairs<<<(B + 255) / 256, 256, 0, stream>>>(pairs, flags, B);
    k_convert_w<<<(D * D / 4 + 255) / 256, 256, 0, stream>>>(Wdb, Wda, Wb, Wa);
    k_tables<<<NTAB, 256, 0, stream>>>(db, da, W1b, W2b, W1a, W2a, flags, T1b, T2b, Ta);
    k_main<<<B / BM, 512, 0, stream>>>(xb, xa, Wb, Wa, bdb, bda, Wpb, Wpa, pairs,
                                       T1b, T2b, Ta, bpb, bpa, b1b, b2b, b1a, b2a, out);
}

// Round 2
// 517.366 us; speedup vs baseline: 1.0478x; 1.0478x over previous
//
#include <hip/hip_runtime.h>
#include <hip/hip_bf16.h>

#define D 768
#define BM 64
#define BK 64
#define LDK 72           // chunk row stride in shorts: 144 B, 16B-aligned, +8 pad
#define NCH 12           // D / BK
#define NWAVE 8
#define NTAB 512         // ND
#define NS 64

typedef short short8v __attribute__((ext_vector_type(8)));
typedef float f32x4 __attribute__((ext_vector_type(4)));

static __device__ __forceinline__ unsigned short f2bf(float f) {
    union { float f; unsigned u; } v; v.f = f;
    unsigned r = v.u + 0x7fffu + ((v.u >> 16) & 1u);   // RNE
    return (unsigned short)(r >> 16);
}

static __device__ __forceinline__ float fast_tanh(float x) {
    float e = __expf(2.0f * x);
    return 1.0f - 2.0f * __builtin_amdgcn_rcpf(e + 1.0f);
}

static __device__ __forceinline__ float dot4(float4 a, float4 b) {
    return a.x * b.x + a.y * b.y + a.z * b.z + a.w * b.w;
}

// ---------------- pairs scan: mark live table rows ----------------
__global__ void k_scan_pairs(const int* __restrict__ pairs, int* __restrict__ flags, int B) {
    int i = blockIdx.x * blockDim.x + threadIdx.x;
    if (i < B) {
        int idx = pairs[(size_t)i * 3];
        if (idx >= 0 && idx < NTAB) atomicOr(&flags[idx], 1);
    }
}

// ---------------- fused: gather tables (blocks < NTAB*4) + W fp32->bf16 (rest) ----------------
__global__ void k_tables_conv(const float* __restrict__ db, const float* __restrict__ da,
                              const float* __restrict__ W1b, const float* __restrict__ W2b,
                              const float* __restrict__ W1a, const float* __restrict__ W2a,
                              const int* __restrict__ flags,
                              float* __restrict__ T1b, float* __restrict__ T2b, float* __restrict__ Ta,
                              const float* __restrict__ wb_f, const float* __restrict__ wa_f,
                              unsigned short* __restrict__ wb, unsigned short* __restrict__ wa) {
    int bid = blockIdx.x;
    if (bid >= NTAB * 4) {
        // ---- weight conversion part ----
        int i = (bid - NTAB * 4) * 256 + threadIdx.x;
        if (i < D * D / 4) {
            float4 vb = ((const float4*)wb_f)[i];
            float4 va = ((const float4*)wa_f)[i];
            ushort4 ub = { f2bf(vb.x), f2bf(vb.y), f2bf(vb.z), f2bf(vb.w) };
            ushort4 ua = { f2bf(va.x), f2bf(va.y), f2bf(va.z), f2bf(va.w) };
            ((ushort4*)wb)[i] = ub;
            ((ushort4*)wa)[i] = ua;
        }
        return;
    }
    int d = bid >> 2;
    int q = bid & 3;
    if (!flags[d]) return;
    int lane = threadIdx.x & 63;
    int wid = threadIdx.x >> 6;                         // 0..3

    float4 a0[3], a1[3], b0[3], b1[3], c0[3], c1[3];
    #pragma unroll
    for (int i = 0; i < 3; ++i) {
        a0[i] = ((const float4*)W1b)[lane + 64 * i];
        a1[i] = ((const float4*)(W1b + D))[lane + 64 * i];
        b0[i] = ((const float4*)W2b)[lane + 64 * i];
        b1[i] = ((const float4*)(W2b + D))[lane + 64 * i];
        float4 p = ((const float4*)W1a)[lane + 64 * i];
        float4 qv = ((const float4*)W2a)[lane + 64 * i];
        c0[i] = make_float4(p.x + qv.x, p.y + qv.y, p.z + qv.z, p.w + qv.w);
        p = ((const float4*)(W1a + D))[lane + 64 * i];
        qv = ((const float4*)(W2a + D))[lane + 64 * i];
        c1[i] = make_float4(p.x + qv.x, p.y + qv.y, p.z + qv.z, p.w + qv.w);
    }

    #pragma unroll
    for (int si = 0; si < 4; ++si) {
        int s = q * 16 + wid + si * 4;
        size_t roff = ((size_t)d * NS + s) * D;
        const float4* rb = (const float4*)(db + roff);
        const float4* ra = (const float4*)(da + roff);
        float sa0 = 0, sa1 = 0, sb0 = 0, sb1 = 0, sc0 = 0, sc1 = 0;
        #pragma unroll
        for (int i = 0; i < 3; ++i) {
            float4 xb = rb[lane + 64 * i];
            float4 xa = ra[lane + 64 * i];
            sa0 += dot4(xb, a0[i]); sa1 += dot4(xb, a1[i]);
            sb0 += dot4(xb, b0[i]); sb1 += dot4(xb, b1[i]);
            sc0 += dot4(xa, c0[i]); sc1 += dot4(xa, c1[i]);
        }
        #pragma unroll
        for (int off = 32; off; off >>= 1) {
            sa0 += __shfl_xor(sa0, off); sa1 += __shfl_xor(sa1, off);
            sb0 += __shfl_xor(sb0, off); sb1 += __shfl_xor(sb1, off);
            sc0 += __shfl_xor(sc0, off); sc1 += __shfl_xor(sc1, off);
        }
        if (lane == 0) {
            size_t o = ((size_t)d * NS + s) * 2;
            T1b[o] = sa0; T1b[o + 1] = sa1;
            T2b[o] = sb0; T2b[o + 1] = sb1;
            Ta[o]  = sc0; Ta[o + 1]  = sc1;
        }
    }
}

// ---------------- fused main: K-chunked double-buffered bf16 MFMA + tanh + proj + gather ----------------
__global__ __launch_bounds__(512, 1)
void k_main(const float* __restrict__ xbert, const float* __restrict__ xalb,
            const unsigned short* __restrict__ wb, const unsigned short* __restrict__ wa,
            const float* __restrict__ bdb, const float* __restrict__ bda,
            const float* __restrict__ wpb, const float* __restrict__ wpa,
            const int* __restrict__ pairs,
            const float* __restrict__ T1b, const float* __restrict__ T2b, const float* __restrict__ Ta,
            const float* __restrict__ bpb, const float* __restrict__ bpa,
            const float* __restrict__ b1b, const float* __restrict__ b2b,
            const float* __restrict__ b1a, const float* __restrict__ b2a,
            float* __restrict__ out) {
    __shared__ short xs[2][BM * LDK];                    // 2 x 9216 B = 18,432 B
    __shared__ float outp[NWAVE][BM][2];                 // 4,096 B

    const int tid = threadIdx.x;
    const int lane = tid & 63;
    const int wid = tid >> 6;                            // 0..7
    const int l15 = lane & 15;
    const int lhi = lane >> 4;                           // 0..3
    const int nb = wid * 96;                             // this wave's 96 cols

    // staging coords: thread handles row srow, float cols [sc8*4, sc8*4+4) and +32
    const int srow = tid >> 3;                           // 0..63
    const int sc8 = tid & 7;                             // 0..7
    const size_t xoff = ((size_t)blockIdx.x * BM + srow) * D + sc8 * 4;

    float outv = 0.0f;
    f32x4 acc[4][6];
    #pragma unroll
    for (int mi = 0; mi < 4; ++mi)
        #pragma unroll
        for (int ni = 0; ni < 6; ++ni)
            acc[mi][ni] = (f32x4){0.f, 0.f, 0.f, 0.f};

    float4 rA, rB;

    // ---- prologue: stage chunk 0 (model 0) ----
    {
        const float* p = xbert + xoff;
        rA = *(const float4*)p;
        rB = *(const float4*)(p + 32);
        short* dst = &xs[0][srow * LDK + sc8 * 4];
        ushort4 ua = { f2bf(rA.x), f2bf(rA.y), f2bf(rA.z), f2bf(rA.w) };
        ushort4 ub = { f2bf(rB.x), f2bf(rB.y), f2bf(rB.z), f2bf(rB.w) };
        *(ushort4*)dst = ua;
        *(ushort4*)(dst + 32) = ub;
    }
    __syncthreads();

    for (int c = 0; c < 2 * NCH; ++c) {
        const int m = (c < NCH) ? 0 : 1;
        const int lc = c - m * NCH;
        const bool has_next = (c + 1 < 2 * NCH);

        // ---- issue next chunk's global loads (consumed just before the barrier) ----
        if (has_next) {
            const float* xg2 = (c + 1 < NCH) ? xbert : xalb;
            const int lc2 = (c + 1) - ((c + 1 < NCH) ? 0 : NCH);
            const float* p = xg2 + xoff + lc2 * BK;
            rA = *(const float4*)p;
            rB = *(const float4*)(p + 32);
        }

        // ---- compute current chunk ----
        const short* xb_ = &xs[c & 1][0];
        const short* wq = (const short*)(m ? wa : wb) + (size_t)(nb + l15) * D + lc * BK + lhi * 8;
        #pragma unroll
        for (int klo = 0; klo < 2; ++klo) {
            short8v av[4], bv[6];
            #pragma unroll
            for (int mi = 0; mi < 4; ++mi)
                av[mi] = *(const short8v*)(xb_ + (mi * 16 + l15) * LDK + klo * 32 + lhi * 8);
            #pragma unroll
            for (int ni = 0; ni < 6; ++ni)
                bv[ni] = *(const short8v*)(wq + (size_t)ni * 16 * D + klo * 32);
            #pragma unroll
            for (int mi = 0; mi < 4; ++mi)
                #pragma unroll
                for (int ni = 0; ni < 6; ++ni)
                    acc[mi][ni] = __builtin_amdgcn_mfma_f32_16x16x32_bf16(av[mi], bv[ni], acc[mi][ni], 0, 0, 0);
        }

        // ---- write next chunk to the other LDS buffer ----
        if (has_next) {
            short* dst = &xs[(c + 1) & 1][srow * LDK + sc8 * 4];
            ushort4 ua = { f2bf(rA.x), f2bf(rA.y), f2bf(rA.z), f2bf(rA.w) };
            ushort4 ub = { f2bf(rB.x), f2bf(rB.y), f2bf(rB.z), f2bf(rB.w) };
            *(ushort4*)dst = ua;
            *(ushort4*)(dst + 32) = ub;
        }

        if (lc == NCH - 1) {
            // ---- epilogue for model m: tanh + project to 2 cols ----
            const float* bd = m ? bda : bdb;
            const float* wp = m ? wpa : wpb;
            float bdv[6], w0v[6], w1v[6];
            #pragma unroll
            for (int ni = 0; ni < 6; ++ni) {
                int n = nb + ni * 16 + l15;
                bdv[ni] = bd[n];
                w0v[ni] = wp[n];
                w1v[ni] = wp[D + n];
            }
            float ps[4][4][2] = {};
            #pragma unroll
            for (int mi = 0; mi < 4; ++mi)
                #pragma unroll
                for (int ni = 0; ni < 6; ++ni)
                    #pragma unroll
                    for (int r = 0; r < 4; ++r) {
                        float t = fast_tanh(acc[mi][ni][r] + bdv[ni]);
                        ps[mi][r][0] += t * w0v[ni];
                        ps[mi][r][1] += t * w1v[ni];
                    }
            #pragma unroll
            for (int mi = 0; mi < 4; ++mi)
                #pragma unroll
                for (int r = 0; r < 4; ++r)
                    #pragma unroll
                    for (int cc = 0; cc < 2; ++cc) {
                        float v = ps[mi][r][cc];
                        v += __shfl_xor(v, 1);
                        v += __shfl_xor(v, 2);
                        v += __shfl_xor(v, 4);
                        v += __shfl_xor(v, 8);
                        ps[mi][r][cc] = v;
                    }
            if (l15 == 0) {
                #pragma unroll
                for (int mi = 0; mi < 4; ++mi)
                    #pragma unroll
                    for (int r = 0; r < 4; ++r) {
                        int row = mi * 16 + lhi * 4 + r;
                        outp[wid][row][0] = ps[mi][r][0];
                        outp[wid][row][1] = ps[mi][r][1];
                    }
            }
            __syncthreads();                              // also orders the dbuf write above
            if (tid < 128) {
                int row = tid >> 1, cc = tid & 1;
                float s = 0.0f;
                #pragma unroll
                for (int w = 0; w < NWAVE; ++w) s += outp[w][row][cc];
                outv += s;
            }
            // reset accumulators for model 1
            #pragma unroll
            for (int mi = 0; mi < 4; ++mi)
                #pragma unroll
                for (int ni = 0; ni < 6; ++ni)
                    acc[mi][ni] = (f32x4){0.f, 0.f, 0.f, 0.f};
        } else {
            __syncthreads();
        }
    }

    // ---- gather + biases + final write ----
    if (tid < 128) {
        int row = tid >> 1, cc = tid & 1;
        size_t R = (size_t)blockIdx.x * BM + row;
        const int* pr = pairs + R * 3;
        int i0 = pr[0], j = pr[1], k2 = pr[2];
        float g = T1b[((size_t)i0 * NS + j) * 2 + cc]
                + T2b[((size_t)i0 * NS + k2) * 2 + cc]
                + Ta[((size_t)i0 * NS + j) * 2 + cc];
        float bias = bpb[cc] + bpa[cc] + b1b[cc] + b2b[cc] + b1a[cc] + b2a[cc];
        out[R * 2 + cc] = outv + g + bias;
    }
}

extern "C" void kernel_launch(void* const* d_in, const int* in_sizes, int n_in,
                              void* d_out, int out_size, void* d_ws, size_t ws_size,
                              hipStream_t stream) {
    const float* xb   = (const float*)d_in[0];
    const float* db   = (const float*)d_in[1];
    const int*   pairs= (const int*)d_in[2];
    const float* xa   = (const float*)d_in[3];
    const float* da   = (const float*)d_in[4];
    const float* Wdb  = (const float*)d_in[5];
    const float* bdb  = (const float*)d_in[6];
    const float* Wda  = (const float*)d_in[7];
    const float* bda  = (const float*)d_in[8];
    const float* Wpb  = (const float*)d_in[9];
    const float* bpb  = (const float*)d_in[10];
    const float* Wpa  = (const float*)d_in[11];
    const float* bpa  = (const float*)d_in[12];
    const float* W1b  = (const float*)d_in[13];
    const float* b1b  = (const float*)d_in[14];
    const float* W2b  = (const float*)d_in[15];
    const float* b2b  = (const float*)d_in[16];
    const float* W1a  = (const float*)d_in[17];
    const float* b1a  = (const float*)d_in[18];
    const float* W2a  = (const float*)d_in[19];
    const float* b2a  = (const float*)d_in[20];
    float* out = (float*)d_out;

    const int B = in_sizes[0] / D;                       // 65536

    char* ws = (char*)d_ws;
    int* flags = (int*)ws;
    unsigned short* Wb = (unsigned short*)(ws + 2048);
    unsigned short* Wa = Wb + D * D;
    float* T1b = (float*)(ws + 2048 + (size_t)2 * D * D * sizeof(unsigned short));
    float* T2b = T1b + NTAB * NS * 2;
    float* Ta  = T2b + NTAB * NS * 2;

    hipMemsetAsync(flags, 0, NTAB * sizeof(int), stream);
    k_scan_pairs<<<(B + 255) / 256, 256, 0, stream>>>(pairs, flags, B);
    const int conv_blocks = (D * D / 4 + 255) / 256;     // 576
    k_tables_conv<<<NTAB * 4 + conv_blocks, 256, 0, stream>>>(
        db, da, W1b, W2b, W1a, W2a, flags, T1b, T2b, Ta, Wdb, Wda, Wb, Wa);
    k_main<<<B / BM, 512, 0, stream>>>(xb, xa, Wb, Wa, bdb, bda, Wpb, Wpa, pairs,
                                       T1b, T2b, Ta, bpb, bpa, b1b, b2b, b1a, b2a, out);
}

// Round 3
// 408.562 us; speedup vs baseline: 1.3269x; 1.2663x over previous
//
#include <hip/hip_runtime.h>
#include <hip/hip_bf16.h>

#define D 768
#define BM 64
#define NCHM 12          // K-chunks per model (768/64)
#define NTAB 512         // ND
#define NS 64
#define NGK 24           // k-granule chunks per row (768/32)
#define NGN 48           // n-groups (768/16)

typedef short short8v __attribute__((ext_vector_type(8)));
typedef float f32x4 __attribute__((ext_vector_type(4)));

typedef const __attribute__((address_space(1))) void* gptr_t;
typedef __attribute__((address_space(3))) void* lptr_t;

static __device__ __forceinline__ void gload16(const void* g, void* l) {
    __builtin_amdgcn_global_load_lds((gptr_t)g, (lptr_t)l, 16, 0, 0);
}

static __device__ __forceinline__ unsigned short f2bf(float f) {
    union { float f; unsigned u; } v; v.f = f;
    unsigned r = v.u + 0x7fffu + ((v.u >> 16) & 1u);   // RNE
    return (unsigned short)(r >> 16);
}

static __device__ __forceinline__ short8v cvt8(float4 a, float4 b) {
    union { short8v v; __hip_bfloat162 h[4]; } u;
    u.h[0] = __float22bfloat162_rn({a.x, a.y});
    u.h[1] = __float22bfloat162_rn({a.z, a.w});
    u.h[2] = __float22bfloat162_rn({b.x, b.y});
    u.h[3] = __float22bfloat162_rn({b.z, b.w});
    return u.v;
}

static __device__ __forceinline__ float fast_tanh(float x) {
    float e = __expf(2.0f * x);
    return 1.0f - 2.0f * __builtin_amdgcn_rcpf(e + 1.0f);
}

static __device__ __forceinline__ float dot4(float4 a, float4 b) {
    return a.x * b.x + a.y * b.y + a.z * b.z + a.w * b.w;
}

// ---------------- pairs scan: mark live table rows ----------------
__global__ void k_scan_pairs(const int* __restrict__ pairs, int* __restrict__ flags, int B) {
    int i = blockIdx.x * blockDim.x + threadIdx.x;
    if (i < B) {
        int idx = pairs[(size_t)i * 3];
        if (idx >= 0 && idx < NTAB) atomicOr(&flags[idx], 1);
    }
}

// ---- fused: gather tables (bid < NTAB*4) + W fp32->bf16 fragment pack (rest) ----
__global__ void k_tables_convq(const float* __restrict__ db, const float* __restrict__ da,
                               const float* __restrict__ W1b, const float* __restrict__ W2b,
                               const float* __restrict__ W1a, const float* __restrict__ W2a,
                               const int* __restrict__ flags,
                               float* __restrict__ T1b, float* __restrict__ T2b, float* __restrict__ Ta,
                               const float* __restrict__ wb_f, const float* __restrict__ wa_f,
                               unsigned short* __restrict__ Wq) {
    int bid = blockIdx.x;
    if (bid >= NTAB * 4) {
        // ---- weight fragment-pack: one wave per (model, n-group, k-chunk) ----
        int widx = (bid - NTAB * 4) * 4 + (threadIdx.x >> 6);
        if (widx >= 2 * NGN * NGK) return;
        int model = widx / (NGN * NGK);
        int rem = widx % (NGN * NGK);
        int g = rem / NGK;
        int kc = rem % NGK;
        int l = threadIdx.x & 63;
        const float* Wsrc = model ? wa_f : wb_f;
        const float* src = Wsrc + (size_t)(g * 16 + (l & 15)) * D + kc * 32 + (l >> 4) * 8;
        float4 f0 = *(const float4*)src;
        float4 f1 = *(const float4*)(src + 4);
        *(short8v*)(Wq + ((((size_t)model * NGN + g) * NGK + kc) * 64 + l) * 8) = cvt8(f0, f1);
        return;
    }
    int d = bid >> 2;
    int q = bid & 3;
    if (!flags[d]) return;
    int lane = threadIdx.x & 63;
    int wid = threadIdx.x >> 6;                         // 0..3

    float4 a0[3], a1[3], b0[3], b1[3], c0[3], c1[3];
    #pragma unroll
    for (int i = 0; i < 3; ++i) {
        a0[i] = ((const float4*)W1b)[lane + 64 * i];
        a1[i] = ((const float4*)(W1b + D))[lane + 64 * i];
        b0[i] = ((const float4*)W2b)[lane + 64 * i];
        b1[i] = ((const float4*)(W2b + D))[lane + 64 * i];
        float4 p = ((const float4*)W1a)[lane + 64 * i];
        float4 qv = ((const float4*)W2a)[lane + 64 * i];
        c0[i] = make_float4(p.x + qv.x, p.y + qv.y, p.z + qv.z, p.w + qv.w);
        p = ((const float4*)(W1a + D))[lane + 64 * i];
        qv = ((const float4*)(W2a + D))[lane + 64 * i];
        c1[i] = make_float4(p.x + qv.x, p.y + qv.y, p.z + qv.z, p.w + qv.w);
    }

    #pragma unroll
    for (int si = 0; si < 4; ++si) {
        int s = q * 16 + wid + si * 4;
        size_t roff = ((size_t)d * NS + s) * D;
        const float4* rb = (const float4*)(db + roff);
        const float4* ra = (const float4*)(da + roff);
        float sa0 = 0, sa1 = 0, sb0 = 0, sb1 = 0, sc0 = 0, sc1 = 0;
        #pragma unroll
        for (int i = 0; i < 3; ++i) {
            float4 xb = rb[lane + 64 * i];
            float4 xa = ra[lane + 64 * i];
            sa0 += dot4(xb, a0[i]); sa1 += dot4(xb, a1[i]);
            sb0 += dot4(xb, b0[i]); sb1 += dot4(xb, b1[i]);
            sc0 += dot4(xa, c0[i]); sc1 += dot4(xa, c1[i]);
        }
        #pragma unroll
        for (int off = 32; off; off >>= 1) {
            sa0 += __shfl_xor(sa0, off); sa1 += __shfl_xor(sa1, off);
            sb0 += __shfl_xor(sb0, off); sb1 += __shfl_xor(sb1, off);
            sc0 += __shfl_xor(sc0, off); sc1 += __shfl_xor(sc1, off);
        }
        if (lane == 0) {
            size_t o = ((size_t)d * NS + s) * 2;
            T1b[o] = sa0; T1b[o + 1] = sa1;
            T2b[o] = sb0; T2b[o + 1] = sb1;
            Ta[o]  = sc0; Ta[o + 1]  = sc1;
        }
    }
}

// ---------------- main: glds-staged fp32 x, fragment-packed bf16 W, fused tanh+proj ----------------
__global__ __launch_bounds__(512, 4)
void k_main(const float* __restrict__ xbert, const float* __restrict__ xalb,
            const unsigned short* __restrict__ Wq,
            const float* __restrict__ bdb, const float* __restrict__ bda,
            const float* __restrict__ wpb, const float* __restrict__ wpa,
            float* __restrict__ pws, int Brows) {
    __shared__ float xs[2][BM * 64];                     // 2 x 16 KB fp32 chunk
    __shared__ float outp[8][BM][2];                     // 4 KB

    const int tid = threadIdx.x;
    const int lane = tid & 63;
    const int wid = tid >> 6;                            // 0..7
    const int l15 = lane & 15;
    const int lhi = lane >> 4;                           // 0..3

    // pair-swizzle: (mtile, nh=0/1) land on the same XCD, dispatched adjacently
    const int bid = blockIdx.x;
    const int nh = (bid >> 3) & 1;
    const int mtile = (bid & 7) | ((bid >> 4) << 3);

    const int nb16 = nh * 24 + wid * 3;                  // wave's first n-group

    // staging source addresses (granule-swizzled: stored g' holds logical g'^row15)
    const int srow = tid >> 4;                           // 0..31
    const int sg = (tid & 15) ^ (srow & 15);             // source granule
    const size_t rowoff1 = ((size_t)mtile * BM + srow) * D + sg * 4;
    const size_t rowoff2 = rowoff1 + (size_t)32 * D;

    float outv = 0.0f;
    f32x4 acc[4][3];
    #pragma unroll
    for (int mi = 0; mi < 4; ++mi)
        #pragma unroll
        for (int ni = 0; ni < 3; ++ni)
            acc[mi][ni] = (f32x4){0.f, 0.f, 0.f, 0.f};

    // prologue: stage chunk 0
    gload16(xbert + rowoff1, &xs[0][wid * 256]);
    gload16(xbert + rowoff2, &xs[0][2048 + wid * 256]);
    __syncthreads();

    for (int c = 0; c < 2 * NCHM; ++c) {
        const int m = (c >= NCHM) ? 1 : 0;
        const int lc = c - m * NCHM;
        const int cb = c & 1;

        // ---- issue next chunk's staging (overlaps with compute below) ----
        if (c + 1 < 2 * NCHM) {
            const int m2 = (c + 1 >= NCHM) ? 1 : 0;
            const int lc2 = (c + 1) - m2 * NCHM;
            const float* xg = m2 ? xalb : xbert;
            gload16(xg + rowoff1 + lc2 * 64, &xs[cb ^ 1][wid * 256]);
            gload16(xg + rowoff2 + lc2 * 64, &xs[cb ^ 1][2048 + wid * 256]);
        }

        // ---- compute current chunk ----
        const float* xc = &xs[cb][0];
        const unsigned short* wbase = Wq + ((size_t)m * NGN + nb16) * (NGK * 512);
        #pragma unroll
        for (int klo = 0; klo < 2; ++klo) {
            const int kc = lc * 2 + klo;
            short8v bv[3];
            #pragma unroll
            for (int ni = 0; ni < 3; ++ni)
                bv[ni] = *(const short8v*)(wbase + ((size_t)ni * NGK + kc) * 512 + lane * 8);
            #pragma unroll
            for (int mi = 0; mi < 4; ++mi) {
                const int row = mi * 16 + l15;
                const int C0 = klo * 8 + lhi * 2;
                float4 fa = *(const float4*)(xc + row * 64 + ((C0) ^ l15) * 4);
                float4 fb = *(const float4*)(xc + row * 64 + ((C0 + 1) ^ l15) * 4);
                short8v av = cvt8(fa, fb);
                #pragma unroll
                for (int ni = 0; ni < 3; ++ni)
                    acc[mi][ni] = __builtin_amdgcn_mfma_f32_16x16x32_bf16(av, bv[ni], acc[mi][ni], 0, 0, 0);
            }
        }

        if (lc == NCHM - 1) {
            // ---- epilogue for model m: tanh + 2-col projection ----
            const float* bd = m ? bda : bdb;
            const float* wp = m ? wpa : wpb;
            float bdv[3], w0v[3], w1v[3];
            #pragma unroll
            for (int ni = 0; ni < 3; ++ni) {
                int n = nh * 384 + wid * 48 + ni * 16 + l15;
                bdv[ni] = bd[n];
                w0v[ni] = wp[n];
                w1v[ni] = wp[D + n];
            }
            float ps[4][4][2] = {};
            #pragma unroll
            for (int mi = 0; mi < 4; ++mi)
                #pragma unroll
                for (int ni = 0; ni < 3; ++ni)
                    #pragma unroll
                    for (int r = 0; r < 4; ++r) {
                        float t = fast_tanh(acc[mi][ni][r] + bdv[ni]);
                        ps[mi][r][0] += t * w0v[ni];
                        ps[mi][r][1] += t * w1v[ni];
                    }
            #pragma unroll
            for (int mi = 0; mi < 4; ++mi)
                #pragma unroll
                for (int r = 0; r < 4; ++r)
                    #pragma unroll
                    for (int cc = 0; cc < 2; ++cc) {
                        float v = ps[mi][r][cc];
                        v += __shfl_xor(v, 1);
                        v += __shfl_xor(v, 2);
                        v += __shfl_xor(v, 4);
                        v += __shfl_xor(v, 8);
                        ps[mi][r][cc] = v;
                    }
            if (l15 == 0) {
                #pragma unroll
                for (int mi = 0; mi < 4; ++mi)
                    #pragma unroll
                    for (int r = 0; r < 4; ++r) {
                        int row = mi * 16 + lhi * 4 + r;
                        outp[wid][row][0] = ps[mi][r][0];
                        outp[wid][row][1] = ps[mi][r][1];
                    }
            }
            __syncthreads();                             // serves as the chunk barrier too
            if (tid < 128) {
                int row = tid >> 1, cc = tid & 1;
                float s = 0.0f;
                #pragma unroll
                for (int w = 0; w < 8; ++w) s += outp[w][row][cc];
                outv += s;
            }
            #pragma unroll
            for (int mi = 0; mi < 4; ++mi)
                #pragma unroll
                for (int ni = 0; ni < 3; ++ni)
                    acc[mi][ni] = (f32x4){0.f, 0.f, 0.f, 0.f};
        } else {
            __syncthreads();
        }
    }

    // ---- write this block's partial (per n-half) ----
    if (tid < 128) {
        int row = tid >> 1, cc = tid & 1;
        size_t R = (size_t)mtile * BM + row;
        pws[((size_t)nh * Brows + R) * 2 + cc] = outv;
    }
}

// ---------------- combine: n-half partials + gather + biases ----------------
__global__ void k_combine(const float* __restrict__ pws, const int* __restrict__ pairs,
                          const float* __restrict__ T1b, const float* __restrict__ T2b,
                          const float* __restrict__ Ta,
                          const float* __restrict__ bpb, const float* __restrict__ bpa,
                          const float* __restrict__ b1b, const float* __restrict__ b2b,
                          const float* __restrict__ b1a, const float* __restrict__ b2a,
                          float* __restrict__ out, int B) {
    int r = blockIdx.x * blockDim.x + threadIdx.x;
    if (r >= B) return;
    const int* pr = pairs + (size_t)r * 3;
    int i0 = pr[0], j = pr[1], k2 = pr[2];
    #pragma unroll
    for (int c = 0; c < 2; ++c) {
        float g = T1b[((size_t)i0 * NS + j) * 2 + c]
                + T2b[((size_t)i0 * NS + k2) * 2 + c]
                + Ta[((size_t)i0 * NS + j) * 2 + c];
        float bias = bpb[c] + bpa[c] + b1b[c] + b2b[c] + b1a[c] + b2a[c];
        out[(size_t)r * 2 + c] = pws[(size_t)r * 2 + c] + pws[((size_t)B + r) * 2 + c] + g + bias;
    }
}

extern "C" void kernel_launch(void* const* d_in, const int* in_sizes, int n_in,
                              void* d_out, int out_size, void* d_ws, size_t ws_size,
                              hipStream_t stream) {
    const float* xb   = (const float*)d_in[0];
    const float* db   = (const float*)d_in[1];
    const int*   pairs= (const int*)d_in[2];
    const float* xa   = (const float*)d_in[3];
    const float* da   = (const float*)d_in[4];
    const float* Wdb  = (const float*)d_in[5];
    const float* bdb  = (const float*)d_in[6];
    const float* Wda  = (const float*)d_in[7];
    const float* bda  = (const float*)d_in[8];
    const float* Wpb  = (const float*)d_in[9];
    const float* bpb  = (const float*)d_in[10];
    const float* Wpa  = (const float*)d_in[11];
    const float* bpa  = (const float*)d_in[12];
    const float* W1b  = (const float*)d_in[13];
    const float* b1b  = (const float*)d_in[14];
    const float* W2b  = (const float*)d_in[15];
    const float* b2b  = (const float*)d_in[16];
    const float* W1a  = (const float*)d_in[17];
    const float* b1a  = (const float*)d_in[18];
    const float* W2a  = (const float*)d_in[19];
    const float* b2a  = (const float*)d_in[20];
    float* out = (float*)d_out;

    const int B = in_sizes[0] / D;                       // 65536

    char* ws = (char*)d_ws;
    int* flags = (int*)ws;                               // 2048 B
    unsigned short* Wq = (unsigned short*)(ws + 2048);   // 2*768*768*2 = 2,359,296 B
    float* T1b = (float*)(ws + 2048 + 2359296);
    float* T2b = T1b + NTAB * NS * 2;
    float* Ta  = T2b + NTAB * NS * 2;
    float* pws = Ta + NTAB * NS * 2;                     // 2*B*2 floats

    hipMemsetAsync(flags, 0, NTAB * sizeof(int), stream);
    k_scan_pairs<<<(B + 255) / 256, 256, 0, stream>>>(pairs, flags, B);
    const int conv_blocks = (2 * NGN * NGK + 3) / 4;     // 576
    k_tables_convq<<<NTAB * 4 + conv_blocks, 256, 0, stream>>>(
        db, da, W1b, W2b, W1a, W2a, flags, T1b, T2b, Ta, Wdb, Wda, Wq);
    k_main<<<(B / BM) * 2, 512, 0, stream>>>(xb, xa, Wq, bdb, bda, Wpb, Wpa, pws, B);
    k_combine<<<(B + 255) / 256, 256, 0, stream>>>(pws, pairs, T1b, T2b, Ta,
                                                   bpb, bpa, b1b, b2b, b1a, b2a, out, B);
}

// Round 4
// 372.877 us; speedup vs baseline: 1.4538x; 1.0957x over previous
//
#include <hip/hip_runtime.h>
#include <hip/hip_bf16.h>

#define D 768
#define BM 64
#define NCHM 12          // K-chunks per model (768/64)
#define NTAB 512         // ND
#define NS 64
#define NGK 24           // k-granule chunks per row (768/32)
#define NGN 48           // n-groups (768/16)

typedef short short8v __attribute__((ext_vector_type(8)));
typedef short short4v __attribute__((ext_vector_type(4)));
typedef float f32x4 __attribute__((ext_vector_type(4)));

typedef const __attribute__((address_space(1))) void* gptr_t;
typedef __attribute__((address_space(3))) void* lptr_t;

static __device__ __forceinline__ void gload16(const void* g, void* l) {
    __builtin_amdgcn_global_load_lds((gptr_t)g, (lptr_t)l, 16, 0, 0);
}

static __device__ __forceinline__ short8v cvt8(float4 a, float4 b) {
    union { short8v v; __hip_bfloat162 h[4]; } u;
    u.h[0] = __float22bfloat162_rn({a.x, a.y});
    u.h[1] = __float22bfloat162_rn({a.z, a.w});
    u.h[2] = __float22bfloat162_rn({b.x, b.y});
    u.h[3] = __float22bfloat162_rn({b.z, b.w});
    return u.v;
}

static __device__ __forceinline__ short4v cvt4(float4 a) {
    union { short4v v; __hip_bfloat162 h[2]; } u;
    u.h[0] = __float22bfloat162_rn({a.x, a.y});
    u.h[1] = __float22bfloat162_rn({a.z, a.w});
    return u.v;
}

static __device__ __forceinline__ float fast_tanh(float x) {
    float e = __expf(2.0f * x);
    return 1.0f - 2.0f * __builtin_amdgcn_rcpf(e + 1.0f);
}

static __device__ __forceinline__ float dot4(float4 a, float4 b) {
    return a.x * b.x + a.y * b.y + a.z * b.z + a.w * b.w;
}

// ---------------- pairs scan: mark live table rows ----------------
__global__ void k_scan_pairs(const int* __restrict__ pairs, int* __restrict__ flags, int B) {
    int i = blockIdx.x * blockDim.x + threadIdx.x;
    if (i < B) {
        int idx = pairs[(size_t)i * 3];
        if (idx >= 0 && idx < NTAB) atomicOr(&flags[idx], 1);
    }
}

// ---- fused: gather tables (bid < NTAB*4) + W fp32->bf16 fragment pack (rest) ----
__global__ void k_tables_convq(const float* __restrict__ db, const float* __restrict__ da,
                               const float* __restrict__ W1b, const float* __restrict__ W2b,
                               const float* __restrict__ W1a, const float* __restrict__ W2a,
                               const int* __restrict__ flags,
                               float* __restrict__ T1b, float* __restrict__ T2b, float* __restrict__ Ta,
                               const float* __restrict__ wb_f, const float* __restrict__ wa_f,
                               unsigned short* __restrict__ Wq) {
    int bid = blockIdx.x;
    if (bid >= NTAB * 4) {
        // ---- weight fragment-pack: one wave per (model, n-group, k-chunk) ----
        int widx = (bid - NTAB * 4) * 4 + (threadIdx.x >> 6);
        if (widx >= 2 * NGN * NGK) return;
        int model = widx / (NGN * NGK);
        int rem = widx % (NGN * NGK);
        int g = rem / NGK;
        int kc = rem % NGK;
        int l = threadIdx.x & 63;
        const float* Wsrc = model ? wa_f : wb_f;
        const float* src = Wsrc + (size_t)(g * 16 + (l & 15)) * D + kc * 32 + (l >> 4) * 8;
        float4 f0 = *(const float4*)src;
        float4 f1 = *(const float4*)(src + 4);
        *(short8v*)(Wq + ((((size_t)model * NGN + g) * NGK + kc) * 64 + l) * 8) = cvt8(f0, f1);
        return;
    }
    int d = bid >> 2;
    int q = bid & 3;
    if (!flags[d]) return;
    int lane = threadIdx.x & 63;
    int wid = threadIdx.x >> 6;                         // 0..3

    float4 a0[3], a1[3], b0[3], b1[3], c0[3], c1[3];
    #pragma unroll
    for (int i = 0; i < 3; ++i) {
        a0[i] = ((const float4*)W1b)[lane + 64 * i];
        a1[i] = ((const float4*)(W1b + D))[lane + 64 * i];
        b0[i] = ((const float4*)W2b)[lane + 64 * i];
        b1[i] = ((const float4*)(W2b + D))[lane + 64 * i];
        float4 p = ((const float4*)W1a)[lane + 64 * i];
        float4 qv = ((const float4*)W2a)[lane + 64 * i];
        c0[i] = make_float4(p.x + qv.x, p.y + qv.y, p.z + qv.z, p.w + qv.w);
        p = ((const float4*)(W1a + D))[lane + 64 * i];
        qv = ((const float4*)(W2a + D))[lane + 64 * i];
        c1[i] = make_float4(p.x + qv.x, p.y + qv.y, p.z + qv.z, p.w + qv.w);
    }

    #pragma unroll
    for (int si = 0; si < 4; ++si) {
        int s = q * 16 + wid + si * 4;
        size_t roff = ((size_t)d * NS + s) * D;
        const float4* rb = (const float4*)(db + roff);
        const float4* ra = (const float4*)(da + roff);
        float sa0 = 0, sa1 = 0, sb0 = 0, sb1 = 0, sc0 = 0, sc1 = 0;
        #pragma unroll
        for (int i = 0; i < 3; ++i) {
            float4 xb = rb[lane + 64 * i];
            float4 xa = ra[lane + 64 * i];
            sa0 += dot4(xb, a0[i]); sa1 += dot4(xb, a1[i]);
            sb0 += dot4(xb, b0[i]); sb1 += dot4(xb, b1[i]);
            sc0 += dot4(xa, c0[i]); sc1 += dot4(xa, c1[i]);
        }
        #pragma unroll
        for (int off = 32; off; off >>= 1) {
            sa0 += __shfl_xor(sa0, off); sa1 += __shfl_xor(sa1, off);
            sb0 += __shfl_xor(sb0, off); sb1 += __shfl_xor(sb1, off);
            sc0 += __shfl_xor(sc0, off); sc1 += __shfl_xor(sc1, off);
        }
        if (lane == 0) {
            size_t o = ((size_t)d * NS + s) * 2;
            T1b[o] = sa0; T1b[o + 1] = sa1;
            T2b[o] = sb0; T2b[o + 1] = sb1;
            Ta[o]  = sc0; Ta[o + 1]  = sc1;
        }
    }
}

// ---------------- main: glds fp32 stage -> cooperative bf16 cvt -> MFMA, fused tanh+proj ----------------
__global__ __launch_bounds__(512, 8)
void k_main(const float* __restrict__ xbert, const float* __restrict__ xalb,
            const unsigned short* __restrict__ Wq,
            const float* __restrict__ bdb, const float* __restrict__ bda,
            const float* __restrict__ wpb, const float* __restrict__ wpa,
            float* __restrict__ pws, int Brows) {
    __shared__ __align__(16) float xs32[2][BM * 64];     // 2 x 16 KB fp32 chunks
    __shared__ __align__(16) short xsb[2][BM * 64];      // 2 x  8 KB bf16 chunks (row-XOR swizzled)
    __shared__ float outp[8][BM][2];                     // 4 KB

    const int tid = threadIdx.x;
    const int lane = tid & 63;
    const int wid = tid >> 6;                            // 0..7
    const int l15 = lane & 15;
    const int lhi = lane >> 4;                           // 0..3
    const int xorv = (l15 & 7) << 4;                     // A-frag read swizzle

    // pair-swizzle: (mtile, nh=0/1) land on the same XCD, dispatched adjacently
    const int bid = blockIdx.x;
    const int nh = (bid >> 3) & 1;
    const int mtile = (bid & 7) | ((bid >> 4) << 3);

    const int nb16 = nh * 24 + wid * 3;                  // wave's first n-group

    // staging: thread t -> row (t>>4), float cols (t&15)*4..+4 (linear), plus +32 rows
    const int srow = tid >> 4;                           // 0..31
    const size_t rowoff1 = ((size_t)mtile * BM + srow) * D + (tid & 15) * 4;
    const size_t rowoff2 = rowoff1 + (size_t)32 * D;

    // converter: thread t reads its own staged float4s, writes swizzled bf16
    const int cr = tid >> 4;                             // row 0..31 (and +32)
    const int cc2 = (tid & 15) * 8;                      // byte col offset in bf16 row
    const int cvw0 = cr * 128 + (cc2 ^ ((cr & 7) << 4)); // byte offsets (r&7 == (r+32)&7)
    const int cvw1 = (cr + 32) * 128 + (cc2 ^ ((cr & 7) << 4));

    float outv = 0.0f;
    f32x4 acc[4][3];
    #pragma unroll
    for (int mi = 0; mi < 4; ++mi)
        #pragma unroll
        for (int ni = 0; ni < 3; ++ni)
            acc[mi][ni] = (f32x4){0.f, 0.f, 0.f, 0.f};

    // chunk source addressing
    #define STAGE(cc, fbuf)                                                      \
        do {                                                                     \
            const int m_ = ((cc) >= NCHM) ? 1 : 0;                               \
            const float* xg_ = m_ ? xalb : xbert;                                \
            const int lc_ = (cc) - m_ * NCHM;                                    \
            gload16(xg_ + rowoff1 + lc_ * 64, &xs32[fbuf][wid * 256]);           \
            gload16(xg_ + rowoff2 + lc_ * 64, &xs32[fbuf][2048 + wid * 256]);    \
        } while (0)

    #define CVT(sbuf, dbuf)                                                      \
        do {                                                                     \
            float4 fa_ = *(const float4*)&xs32[sbuf][tid * 4];                   \
            float4 fb_ = *(const float4*)&xs32[sbuf][2048 + tid * 4];            \
            *(short4v*)((char*)&xsb[dbuf][0] + cvw0) = cvt4(fa_);                \
            *(short4v*)((char*)&xsb[dbuf][0] + cvw1) = cvt4(fb_);                \
        } while (0)

    // ---- prologue ----
    STAGE(0, 0);
    __syncthreads();
    CVT(0, 0);                                           // chunk 0 -> xsb[0]
    STAGE(1, 1);
    __syncthreads();

    for (int c = 0; c < 2 * NCHM; ++c) {
        const int m = (c >= NCHM) ? 1 : 0;
        const int lc = c - m * NCHM;
        const int cb = c & 1;

        // ---- issue chunk c+2 staging into the fp32 buffer freed last iter ----
        if (c + 2 < 2 * NCHM) STAGE(c + 2, cb);

        // ---- MFMA chunk c from bf16 buffer ----
        {
            const char* xbase = (const char*)&xsb[cb][0];
            const unsigned short* wbase = Wq + ((size_t)m * NGN + nb16) * (NGK * 512);
            #pragma unroll
            for (int klo = 0; klo < 2; ++klo) {
                const int kc = lc * 2 + klo;
                short8v bv[3];
                #pragma unroll
                for (int ni = 0; ni < 3; ++ni)
                    bv[ni] = *(const short8v*)(wbase + ((size_t)ni * NGK + kc) * 512 + lane * 8);
                #pragma unroll
                for (int mi = 0; mi < 4; ++mi) {
                    short8v av = *(const short8v*)(xbase + (mi * 16 + l15) * 128 +
                                                   ((klo * 64 + lhi * 16) ^ xorv));
                    #pragma unroll
                    for (int ni = 0; ni < 3; ++ni)
                        acc[mi][ni] = __builtin_amdgcn_mfma_f32_16x16x32_bf16(av, bv[ni], acc[mi][ni], 0, 0, 0);
                }
            }
        }

        // ---- cooperative cvt of chunk c+1 (fp32 LDS -> swizzled bf16 LDS) ----
        if (c + 1 < 2 * NCHM) CVT(cb ^ 1, cb ^ 1);

        if (lc == NCHM - 1) {
            // ---- epilogue for model m: tanh + 2-col projection ----
            const float* bd = m ? bda : bdb;
            const float* wp = m ? wpa : wpb;
            float bdv[3], w0v[3], w1v[3];
            #pragma unroll
            for (int ni = 0; ni < 3; ++ni) {
                int n = nh * 384 + wid * 48 + ni * 16 + l15;
                bdv[ni] = bd[n];
                w0v[ni] = wp[n];
                w1v[ni] = wp[D + n];
            }
            float ps[4][4][2] = {};
            #pragma unroll
            for (int mi = 0; mi < 4; ++mi)
                #pragma unroll
                for (int ni = 0; ni < 3; ++ni)
                    #pragma unroll
                    for (int r = 0; r < 4; ++r) {
                        float t = fast_tanh(acc[mi][ni][r] + bdv[ni]);
                        ps[mi][r][0] += t * w0v[ni];
                        ps[mi][r][1] += t * w1v[ni];
                    }
            #pragma unroll
            for (int mi = 0; mi < 4; ++mi)
                #pragma unroll
                for (int r = 0; r < 4; ++r)
                    #pragma unroll
                    for (int cc = 0; cc < 2; ++cc) {
                        float v = ps[mi][r][cc];
                        v += __shfl_xor(v, 1);
                        v += __shfl_xor(v, 2);
                        v += __shfl_xor(v, 4);
                        v += __shfl_xor(v, 8);
                        ps[mi][r][cc] = v;
                    }
            if (l15 == 0) {
                #pragma unroll
                for (int mi = 0; mi < 4; ++mi)
                    #pragma unroll
                    for (int r = 0; r < 4; ++r) {
                        int row = mi * 16 + lhi * 4 + r;
                        outp[wid][row][0] = ps[mi][r][0];
                        outp[wid][row][1] = ps[mi][r][1];
                    }
            }
            __syncthreads();                             // serves as the chunk barrier too
            if (tid < 128) {
                int row = tid >> 1, cc = tid & 1;
                float s = 0.0f;
                #pragma unroll
                for (int w = 0; w < 8; ++w) s += outp[w][row][cc];
                outv += s;
            }
            #pragma unroll
            for (int mi = 0; mi < 4; ++mi)
                #pragma unroll
                for (int ni = 0; ni < 3; ++ni)
                    acc[mi][ni] = (f32x4){0.f, 0.f, 0.f, 0.f};
        } else {
            __syncthreads();
        }
    }
    #undef STAGE
    #undef CVT

    // ---- write this block's partial (per n-half) ----
    if (tid < 128) {
        int row = tid >> 1, cc = tid & 1;
        size_t R = (size_t)mtile * BM + row;
        pws[((size_t)nh * Brows + R) * 2 + cc] = outv;
    }
}

// ---------------- combine: n-half partials + gather + biases ----------------
__global__ void k_combine(const float* __restrict__ pws, const int* __restrict__ pairs,
                          const float* __restrict__ T1b, const float* __restrict__ T2b,
                          const float* __restrict__ Ta,
                          const float* __restrict__ bpb, const float* __restrict__ bpa,
                          const float* __restrict__ b1b, const float* __restrict__ b2b,
                          const float* __restrict__ b1a, const float* __restrict__ b2a,
                          float* __restrict__ out, int B) {
    int r = blockIdx.x * blockDim.x + threadIdx.x;
    if (r >= B) return;
    const int* pr = pairs + (size_t)r * 3;
    int i0 = pr[0], j = pr[1], k2 = pr[2];
    #pragma unroll
    for (int c = 0; c < 2; ++c) {
        float g = T1b[((size_t)i0 * NS + j) * 2 + c]
                + T2b[((size_t)i0 * NS + k2) * 2 + c]
                + Ta[((size_t)i0 * NS + j) * 2 + c];
        float bias = bpb[c] + bpa[c] + b1b[c] + b2b[c] + b1a[c] + b2a[c];
        out[(size_t)r * 2 + c] = pws[(size_t)r * 2 + c] + pws[((size_t)B + r) * 2 + c] + g + bias;
    }
}

extern "C" void kernel_launch(void* const* d_in, const int* in_sizes, int n_in,
                              void* d_out, int out_size, void* d_ws, size_t ws_size,
                              hipStream_t stream) {
    const float* xb   = (const float*)d_in[0];
    const float* db   = (const float*)d_in[1];
    const int*   pairs= (const int*)d_in[2];
    const float* xa   = (const float*)d_in[3];
    const float* da   = (const float*)d_in[4];
    const float* Wdb  = (const float*)d_in[5];
    const float* bdb  = (const float*)d_in[6];
    const float* Wda  = (const float*)d_in[7];
    const float* bda  = (const float*)d_in[8];
    const float* Wpb  = (const float*)d_in[9];
    const float* bpb  = (const float*)d_in[10];
    const float* Wpa  = (const float*)d_in[11];
    const float* bpa  = (const float*)d_in[12];
    const float* W1b  = (const float*)d_in[13];
    const float* b1b  = (const float*)d_in[14];
    const float* W2b  = (const float*)d_in[15];
    const float* b2b  = (const float*)d_in[16];
    const float* W1a  = (const float*)d_in[17];
    const float* b1a  = (const float*)d_in[18];
    const float* W2a  = (const float*)d_in[19];
    const float* b2a  = (const float*)d_in[20];
    float* out = (float*)d_out;

    const int B = in_sizes[0] / D;                       // 65536

    char* ws = (char*)d_ws;
    int* flags = (int*)ws;                               // 2048 B
    unsigned short* Wq = (unsigned short*)(ws + 2048);   // 2*768*768*2 = 2,359,296 B
    float* T1b = (float*)(ws + 2048 + 2359296);
    float* T2b = T1b + NTAB * NS * 2;
    float* Ta  = T2b + NTAB * NS * 2;
    float* pws = Ta + NTAB * NS * 2;                     // 2*B*2 floats

    hipMemsetAsync(flags, 0, NTAB * sizeof(int), stream);
    k_scan_pairs<<<(B + 255) / 256, 256, 0, stream>>>(pairs, flags, B);
    const int conv_blocks = (2 * NGN * NGK + 3) / 4;     // 576
    k_tables_convq<<<NTAB * 4 + conv_blocks, 256, 0, stream>>>(
        db, da, W1b, W2b, W1a, W2a, flags, T1b, T2b, Ta, Wdb, Wda, Wq);
    k_main<<<(B / BM) * 2, 512, 0, stream>>>(xb, xa, Wq, bdb, bda, Wpb, Wpa, pws, B);
    k_combine<<<(B + 255) / 256, 256, 0, stream>>>(pws, pairs, T1b, T2b, Ta,
                                                   bpb, bpa, b1b, b2b, b1a, b2a, out, B);
}